// Round 5
// baseline (610.571 us; speedup 1.0000x reference)
//
#include <hip/hip_runtime.h>

typedef short short8 __attribute__((ext_vector_type(8)));
typedef float f32x4 __attribute__((ext_vector_type(4)));

__device__ __forceinline__ unsigned short f2b(float f) {
    unsigned u = __float_as_uint(f);
    u += 0x7fffu + ((u >> 16) & 1u);          // round-to-nearest-even
    return (unsigned short)(u >> 16);
}
__device__ __forceinline__ float b2f(unsigned short h) {
    return __uint_as_float(((unsigned)h) << 16);
}

// ---------------------------------------------------------------------------
// 3x3 conv, pad 1, stride 1, NHWC bf16, bf16 MFMA fp32 accum.
// Block: 16x16 output pixels x (NW/4) co-blocks of 32 c_out. NW waves.
// Conv staging is per-K-step (32 ch + 4 pad -> 23.3 KB), so C_IN=64 fits the
// same footprint as C_IN=32.
// DEFORM=1: conv output = offsets, packed to bf16 regs, then written to an
// 8 KB s_off in FOUR row-passes (wave p owns sample rows rl in {2p,2p+1}).
// Sample taps come from a 4x(10x10x32ch) LDS neighborhood buffer (aliasing
// the dead conv staging) with exec-masked global fallback for |off|>=1.
// Total LDS ~33.8 KB -> 4 blocks/CU.
// ---------------------------------------------------------------------------
template <int C_IN, int C_OUT, int NW, int DEFORM>
__global__ __launch_bounds__(NW * 64) void conv_s1_mfma(
    const unsigned short* __restrict__ in, const unsigned short* __restrict__ wT,
    const float* __restrict__ bias, unsigned short* __restrict__ out,
    int H, int W, int relu)
{
    constexpr int LDSTR  = 36;               // 32 staged channels + 4 pad
    constexpr int KSTEPS = C_IN / 32;
    constexpr int COPB   = 32 * (NW / 4);
    static_assert(!DEFORM || COPB == 64, "deform fusion expects 64 conv ch/block");
    constexpr int S_CONV = 18 * 18 * LDSTR;              // 11664 ush = 23.3 KB
    constexpr int S_SMP  = DEFORM ? 4 * 100 * 32 : 0;    // 12800 ush = 25.6 KB
    constexpr int S_A    = (S_CONV > S_SMP) ? S_CONV : S_SMP;
    __shared__ __align__(16) unsigned short s_in[S_A];
    __shared__ __align__(16) unsigned short s_off[DEFORM ? 4 * 16 * 64 : 8]; // 8 KB

    const int tid   = threadIdx.x;
    const int wave  = tid >> 6;
    const int wv    = wave & 3;
    const int csub  = wave >> 2;
    const int lane  = tid & 63;
    const int mlane = lane & 15;
    const int quad  = lane >> 4;

    const int nCo  = C_OUT / COPB;
    const int b    = blockIdx.z / nCo;
    const int coB  = (blockIdx.z - b * nCo) * COPB + csub * 32;
    const int row0 = blockIdx.y * 16;
    const int col0 = blockIdx.x * 16;

    f32x4 acc[2][4];
    #pragma unroll
    for (int mt = 0; mt < 2; ++mt)
        #pragma unroll
        for (int t = 0; t < 4; ++t) acc[mt][t] = (f32x4)(0.f);

    #pragma unroll 1
    for (int kk = 0; kk < KSTEPS; ++kk) {
        if (kk) __syncthreads();             // prior conv reads done before restage
        for (int idx = tid; idx < 18 * 18 * 4; idx += NW * 64) {
            int pixel = idx >> 2;
            int ch    = (idx & 3) * 8;
            int pr    = pixel / 18;
            int pc    = pixel - pr * 18;
            int gr = row0 - 1 + pr, gc = col0 - 1 + pc;
            ulonglong2 v; v.x = 0; v.y = 0;
            if ((unsigned)gr < (unsigned)H && (unsigned)gc < (unsigned)W)
                v = *(const ulonglong2*)&in[((b * H + gr) * W + gc) * C_IN + kk * 32 + ch];
            *(ulonglong2*)&s_in[pixel * LDSTR + ch] = v;
        }
        __syncthreads();

        short8 A[2][9];
        #pragma unroll
        for (int mt = 0; mt < 2; ++mt)
            #pragma unroll
            for (int tap = 0; tap < 9; ++tap)
                A[mt][tap] = *(const short8*)&wT[(tap * C_OUT + coB + mt * 16 + mlane) * C_IN
                                                 + kk * 32 + quad * 8];

        const unsigned short* sb =
            &s_in[(wv * 4 * 18 + mlane) * LDSTR + quad * 8];
        #pragma unroll
        for (int t = 0; t < 4; ++t) {
            #pragma unroll
            for (int tap = 0; tap < 9; ++tap) {
                const int dy = tap / 3, dx = tap % 3;
                short8 Bf = *(const short8*)&sb[((t + dy) * 18 + dx) * LDSTR];
                acc[0][t] = __builtin_amdgcn_mfma_f32_16x16x32_bf16(A[0][tap], Bf, acc[0][t], 0, 0, 0);
                acc[1][t] = __builtin_amdgcn_mfma_f32_16x16x32_bf16(A[1][tap], Bf, acc[1][t], 0, 0, 0);
            }
        }
    }

    if (!DEFORM) {
        #pragma unroll
        for (int mt = 0; mt < 2; ++mt) {
            const int cb = coB + mt * 16 + quad * 4;
            float4 bv;
            if (bias) bv = *(const float4*)&bias[cb]; else { bv.x = bv.y = bv.z = bv.w = 0.f; }
            #pragma unroll
            for (int t = 0; t < 4; ++t) {
                const int row = row0 + wv * 4 + t, col = col0 + mlane;
                float o0 = acc[mt][t][0] + bv.x, o1 = acc[mt][t][1] + bv.y;
                float o2 = acc[mt][t][2] + bv.z, o3 = acc[mt][t][3] + bv.w;
                if (relu) {
                    o0 = fmaxf(o0, 0.f); o1 = fmaxf(o1, 0.f);
                    o2 = fmaxf(o2, 0.f); o3 = fmaxf(o3, 0.f);
                }
                ushort4 pk; pk.x = f2b(o0); pk.y = f2b(o1); pk.z = f2b(o2); pk.w = f2b(o3);
                *(ushort4*)&out[((b * H + row) * W + col) * C_OUT + cb] = pk;
            }
        }
    } else {
        const int zb    = blockIdx.z - b * nCo;
        const int zbase = zb * 32;
        const int Hh = H >> 1, Wh = W >> 1;
        const int r8 = blockIdx.y * 8, c8 = blockIdx.x * 8;

        // pack offsets to bf16 in registers (frees acc pressure)
        ushort4 opk[2][4];
        #pragma unroll
        for (int mt = 0; mt < 2; ++mt)
            #pragma unroll
            for (int t = 0; t < 4; ++t) {
                opk[mt][t].x = f2b(acc[mt][t][0]);
                opk[mt][t].y = f2b(acc[mt][t][1]);
                opk[mt][t].z = f2b(acc[mt][t][2]);
                opk[mt][t].w = f2b(acc[mt][t][3]);
            }

        __syncthreads();   // conv reads of s_in complete; s_in reused for samples

        // ---- stage 4 sample neighborhoods (10x10 px x 32 ch) into s_in
        // region reg = ih*2+chf: base (R0,C0) = (r8+ih*Hh, c8+chf*Wh), rows/cols
        // R0-1..R0+8 clamped. Layout: [reg][10r][10c][32ch].
        for (int idx = tid; idx < 1600; idx += NW * 64) {
            const int pixel = idx >> 2;
            const int chq   = (idx & 3) * 8;
            const int reg   = pixel / 100;
            const int rem   = pixel - reg * 100;
            const int rr_   = rem / 10;
            const int cc_   = rem - rr_ * 10;
            int gr = r8 + (reg >> 1) * Hh - 1 + rr_;
            int gc = c8 + (reg & 1)  * Wh - 1 + cc_;
            gr = gr < 0 ? 0 : (gr > H - 1 ? H - 1 : gr);
            gc = gc < 0 ? 0 : (gc > W - 1 ? W - 1 : gc);
            *(ulonglong2*)&s_in[pixel * 32 + chq] =
                *(const ulonglong2*)&in[((b * H + gr) * W + gc) * C_IN + zbase + chq];
        }

        // ---- 4 passes: wave p writes its 4 offset rows, then all threads
        // sample rl in {2p, 2p+1}.
        const int ci   = tid & 31;          // sample channel (within this co-block)
        const int slot = tid >> 5;          // 0..15
        const int cl   = slot >> 1;         // sample col within tile
        const int chf  = slot & 1;          // col-half select
        const int lc   = cl * 2;            // conv-local col (even)
        const unsigned short* xb = in  + (long)b * H * W * C_IN + zbase + ci;
        unsigned short*       ob = out + (long)b * H * W * C_IN + zbase + ci;
        const float Hm1 = (float)(H - 1), Wm1 = (float)(W - 1);
        const int swz0 = (2 * ci) ^ ((lc & 7) << 3);
        const int swz1 = (2 * ci) ^ (((lc + 1) & 7) << 3);

        #pragma unroll
        for (int pass = 0; pass < 4; ++pass) {
            if (wv == pass) {
                #pragma unroll
                for (int mt = 0; mt < 2; ++mt) {
                    const int cb  = csub * 32 + mt * 16 + quad * 4;
                    const int swc = cb ^ ((mlane & 7) << 3);
                    #pragma unroll
                    for (int t = 0; t < 4; ++t)
                        *(ushort4*)&s_off[(t * 16 + mlane) * 64 + swc] = opk[mt][t];
                }
            }
            __syncthreads();

            #pragma unroll
            for (int s2 = 0; s2 < 2; ++s2) {
                const int rl   = pass * 2 + s2;     // sample row in tile
                const int lrow = s2 * 2 + chf;      // conv row & 3
                const int bix  = (lrow * 16 + lc) * 64;
                const ushort2 roP = *(const ushort2*)&s_off[bix +      swz0];
                const ushort2 coP = *(const ushort2*)&s_off[bix + 64 + swz1];
                #pragma unroll
                for (int ih = 0; ih < 2; ++ih) {
                    const int R0 = r8 + ih * Hh, C0 = c8 + chf * Wh;
                    const int rowg = R0 + rl, cg = C0 + cl;
                    const float rr = fminf(fmaxf(b2f(ih ? roP.y : roP.x) + (float)rowg, 0.f), Hm1);
                    const float cc = fminf(fmaxf(b2f(ih ? coP.y : coP.x) + (float)cg,   0.f), Wm1);
                    const float rf = floorf(rr), cf = floorf(cc);
                    const float fr = rr - rf, fc = cc - cf;
                    const int irf = (int)rf, icf = (int)cf;
                    const int dr1 = (fr > 0.f) ? 1 : 0;
                    const int dc1 = (fc > 0.f) ? 1 : 0;
                    const int lr0 = irf - R0 + 1;   // LDS row 0..9 when in-box
                    const int lc0 = icf - C0 + 1;
                    float v00, v01, v10, v11;
                    if ((unsigned)lr0 <= (unsigned)(9 - dr1) &&
                        (unsigned)lc0 <= (unsigned)(9 - dc1)) {
                        const int reg = ih * 2 + chf;
                        const unsigned short* sp =
                            &s_in[(reg * 100 + lr0 * 10 + lc0) * 32 + ci];
                        v00 = b2f(sp[0]);
                        v01 = b2f(sp[dc1 * 32]);
                        v10 = b2f(sp[dr1 * 320]);
                        v11 = b2f(sp[dr1 * 320 + dc1 * 32]);
                    } else {                         // rare: |off| >= 1
                        const int idx00 = (irf * W + icf) * C_IN;
                        const int dr = dr1 * W * C_IN, dc = dc1 * C_IN;
                        v00 = b2f(xb[idx00]);
                        v01 = b2f(xb[idx00 + dc]);
                        v10 = b2f(xb[idx00 + dr]);
                        v11 = b2f(xb[idx00 + dr + dc]);
                    }
                    const float vt = v00 + (v10 - v00) * fr;
                    const float vb = v01 + (v11 - v01) * fr;
                    const float rs = vt + (vb - vt) * fc;
                    ob[(rowg * W + cg) * C_IN] = f2b(rs);
                }
            }
            if (pass < 3) __syncthreads();
        }
    }
}

// ---------------------------------------------------------------------------
// 3x3 conv, pad 1, stride 2, NHWC bf16. Block: 8x8 out px x (NW/4) co-blocks.
// ---------------------------------------------------------------------------
template <int C_IN, int C_OUT, int NW>
__global__ __launch_bounds__(NW * 64) void conv_s2_mfma(
    const unsigned short* __restrict__ in, const unsigned short* __restrict__ wT,
    const float* __restrict__ bias, unsigned short* __restrict__ out,
    int H_in, int W_in, int relu)
{
    constexpr int LDSTR  = C_IN + 8;
    constexpr int KSTEPS = C_IN / 32;
    constexpr int CH8    = C_IN / 8;
    constexpr int COPB   = 32 * (NW / 4);
    __shared__ unsigned short s_in[17 * 17 * LDSTR];

    const int tid   = threadIdx.x;
    const int wave  = tid >> 6;
    const int wv    = wave & 3;
    const int csub  = wave >> 2;
    const int lane  = tid & 63;
    const int mlane = lane & 15;
    const int quad  = lane >> 4;

    const int H_out = H_in >> 1, W_out = W_in >> 1;
    const int nCo   = C_OUT / COPB;
    const int b     = blockIdx.z / nCo;
    const int coB   = (blockIdx.z - b * nCo) * COPB + csub * 32;
    const int orow0 = blockIdx.y * 8, ocol0 = blockIdx.x * 8;
    const int irow0 = orow0 * 2 - 1,  icol0 = ocol0 * 2 - 1;

    for (int idx = tid; idx < 17 * 17 * CH8; idx += NW * 64) {
        int pixel = idx / CH8;
        int ch    = (idx - pixel * CH8) * 8;
        int pr    = pixel / 17;
        int pc    = pixel - pr * 17;
        int gr = irow0 + pr, gc = icol0 + pc;
        ulonglong2 v; v.x = 0; v.y = 0;
        if ((unsigned)gr < (unsigned)H_in && (unsigned)gc < (unsigned)W_in)
            v = *(const ulonglong2*)&in[((b * H_in + gr) * W_in + gc) * C_IN + ch];
        *(ulonglong2*)&s_in[pixel * LDSTR + ch] = v;
    }
    __syncthreads();

    f32x4 acc[2];
    acc[0] = (f32x4)(0.f); acc[1] = (f32x4)(0.f);

    const int plr = wv * 2 + (mlane >> 3);
    const int plc = mlane & 7;

    #pragma unroll 1
    for (int kk = 0; kk < KSTEPS; ++kk) {
        short8 A[2][9];
        #pragma unroll
        for (int mt = 0; mt < 2; ++mt)
            #pragma unroll
            for (int tap = 0; tap < 9; ++tap)
                A[mt][tap] = *(const short8*)&wT[(tap * C_OUT + coB + mt * 16 + mlane) * C_IN
                                                 + kk * 32 + quad * 8];

        const unsigned short* sb0 =
            &s_in[(plr * 2 * 17 + plc * 2) * LDSTR + kk * 32 + quad * 8];
        #pragma unroll
        for (int tap = 0; tap < 9; ++tap) {
            const int dy = tap / 3, dx = tap % 3;
            short8 Bf = *(const short8*)&sb0[(dy * 17 + dx) * LDSTR];
            acc[0] = __builtin_amdgcn_mfma_f32_16x16x32_bf16(A[0][tap], Bf, acc[0], 0, 0, 0);
            acc[1] = __builtin_amdgcn_mfma_f32_16x16x32_bf16(A[1][tap], Bf, acc[1], 0, 0, 0);
        }
    }

    const int row = orow0 + plr, col = ocol0 + plc;
    #pragma unroll
    for (int mt = 0; mt < 2; ++mt) {
        const int cb = coB + mt * 16 + quad * 4;
        float4 bv;
        if (bias) bv = *(const float4*)&bias[cb]; else { bv.x = bv.y = bv.z = bv.w = 0.f; }
        float o0 = acc[mt][0] + bv.x, o1 = acc[mt][1] + bv.y;
        float o2 = acc[mt][2] + bv.z, o3 = acc[mt][3] + bv.w;
        if (relu) {
            o0 = fmaxf(o0, 0.f); o1 = fmaxf(o1, 0.f);
            o2 = fmaxf(o2, 0.f); o3 = fmaxf(o3, 0.f);
        }
        ushort4 pk; pk.x = f2b(o0); pk.y = f2b(o1); pk.z = f2b(o2); pk.w = f2b(o3);
        *(ushort4*)&out[((b * H_out + row) * W_out + col) * C_OUT + cb] = pk;
    }
}

// ---------------------------------------------------------------------------
// x: fp32 NCHW (C=32) -> bf16 NHWC via LDS transpose. Block: 32ch x 64 px.
// ---------------------------------------------------------------------------
__global__ __launch_bounds__(256) void nchw2nhwc(
    const float* __restrict__ x, unsigned short* __restrict__ out, int HW)
{
    __shared__ float s[32][65];
    const int b = blockIdx.y, p0 = blockIdx.x * 64;
    const int tid = threadIdx.x;
    #pragma unroll
    for (int k = 0; k < 8; ++k) {
        int e = tid + k * 256, ci = e >> 6, p = e & 63;
        s[ci][p] = x[(b * 32 + ci) * HW + p0 + p];
    }
    __syncthreads();
    #pragma unroll
    for (int k = 0; k < 8; ++k) {
        int e = tid + k * 256, p = e >> 5, ci = e & 31;
        out[(b * HW + p0 + p) * 32 + ci] = f2b(s[ci][p]);
    }
}

// all 7 weight transforms in one launch: fp32 OIHW -> bf16 [tap][C_out][C_in]
struct WTArgs {
    const float* src[7];
    unsigned short* dst[7];
    int co[7], ci[7], n[7];
};
__global__ __launch_bounds__(256) void wtrans_all(WTArgs a)
{
    const int i = blockIdx.x * 256 + threadIdx.x;
    #pragma unroll
    for (int s = 0; s < 7; ++s) {
        if (i < a.n[s]) {
            const int ci  = i % a.ci[s];
            const int rr  = i / a.ci[s];
            const int co  = rr % a.co[s];
            const int tap = rr / a.co[s];
            a.dst[s][i] = f2b(a.src[s][(co * a.ci[s] + ci) * 9 + tap]);
        }
    }
}

// global avg pool over 32x32, NHWC bf16 (C=32) -> fp32 (B,C)
__global__ __launch_bounds__(256) void avgpool_nhwc(
    const unsigned short* __restrict__ in, float* __restrict__ out)
{
    const int b = blockIdx.x, tid = threadIdx.x;
    const int ci = tid & 31, pg = tid >> 5;
    float s = 0.f;
    for (int k = 0; k < 128; ++k) {
        int p = pg * 128 + k;
        s += b2f(in[(b * 1024 + p) * 32 + ci]);
    }
    __shared__ float red[8][32];
    red[pg][ci] = s;
    __syncthreads();
    if (tid < 32) {
        float t = 0.f;
        #pragma unroll
        for (int j = 0; j < 8; ++j) t += red[j][tid];
        out[b * 32 + tid] = t * (1.f / 1024.f);
    }
}

__global__ __launch_bounds__(256) void sentinel(float* out, int n, float v)
{
    int i = blockIdx.x * 256 + threadIdx.x;
    if (i < n) out[i] = v;
}

extern "C" void kernel_launch(void* const* d_in, const int* in_sizes, int n_in,
                              void* d_out, int out_size, void* d_ws, size_t ws_size,
                              hipStream_t stream) {
    (void)in_sizes; (void)n_in; (void)out_size;
    const float* x   = (const float*)d_in[0];
    const float* w1  = (const float*)d_in[1];
    const float* b1  = (const float*)d_in[2];
    const float* ow1 = (const float*)d_in[3];
    const float* w2  = (const float*)d_in[4];
    const float* b2  = (const float*)d_in[5];
    const float* ow2 = (const float*)d_in[6];
    const float* w3  = (const float*)d_in[7];
    const float* b3  = (const float*)d_in[8];
    const float* ow3 = (const float*)d_in[9];
    const float* w4  = (const float*)d_in[10];
    const float* b4  = (const float*)d_in[11];
    float* out = (float*)d_out;
    unsigned short* wsu = (unsigned short*)d_ws;

    const size_t XB = 0;
    const size_t HA = 33554432;
    const size_t DC = 134217728;
    const size_t WB = 167772160;
    const size_t total_us = WB + 165888;
    if (ws_size < total_us * 2) {
        sentinel<<<2, 256, 0, stream>>>(out, 512, 12345.0f);
        return;
    }
    unsigned short* xb = wsu + XB;
    unsigned short* hA = wsu + HA;
    unsigned short* dC = wsu + DC;
    unsigned short* wt1  = wsu + WB;
    unsigned short* owt1 = wt1 + 9216;
    unsigned short* wt2  = owt1 + 18432;
    unsigned short* owt2 = wt2 + 18432;
    unsigned short* wt3  = owt2 + 73728;
    unsigned short* owt3 = wt3 + 18432;
    unsigned short* wt4  = owt3 + 18432;

    WTArgs wa;
    wa.src[0] = w1;  wa.dst[0] = wt1;  wa.co[0] = 32;  wa.ci[0] = 32; wa.n[0] = 9216;
    wa.src[1] = ow1; wa.dst[1] = owt1; wa.co[1] = 64;  wa.ci[1] = 32; wa.n[1] = 18432;
    wa.src[2] = w2;  wa.dst[2] = wt2;  wa.co[2] = 64;  wa.ci[2] = 32; wa.n[2] = 18432;
    wa.src[3] = ow2; wa.dst[3] = owt2; wa.co[3] = 128; wa.ci[3] = 64; wa.n[3] = 73728;
    wa.src[4] = w3;  wa.dst[4] = wt3;  wa.co[4] = 32;  wa.ci[4] = 64; wa.n[4] = 18432;
    wa.src[5] = ow3; wa.dst[5] = owt3; wa.co[5] = 64;  wa.ci[5] = 32; wa.n[5] = 18432;
    wa.src[6] = w4;  wa.dst[6] = wt4;  wa.co[6] = 32;  wa.ci[6] = 32; wa.n[6] = 9216;
    wtrans_all<<<288, 256, 0, stream>>>(wa);

    nchw2nhwc<<<dim3(1024, 16), 256, 0, stream>>>(x, xb, 65536);

    // L1: conv1 (32->32, 256x256, s1, relu)
    conv_s1_mfma<32, 32, 4, 0><<<dim3(16, 16, 16), 256, 0, stream>>>(xb, wt1, b1, hA, 256, 256, 1);
    // offconv1 (32->64) fused with deformable sampling: hA -> dC
    conv_s1_mfma<32, 64, 8, 1><<<dim3(16, 16, 16), 512, 0, stream>>>(hA, owt1, nullptr, dC, 256, 256, 0);

    // L2: conv2 (32->64, s2) 256->128
    conv_s2_mfma<32, 64, 8><<<dim3(16, 16, 16), 512, 0, stream>>>(dC, wt2, b2, hA, 256, 256, 1);
    // offconv2 (64->128) fused with deform: hA -> dC
    conv_s1_mfma<64, 128, 8, 1><<<dim3(8, 8, 32), 512, 0, stream>>>(hA, owt2, nullptr, dC, 128, 128, 0);

    // L3: conv3 (64->32, s2) 128->64
    conv_s2_mfma<64, 32, 4><<<dim3(8, 8, 16), 256, 0, stream>>>(dC, wt3, b3, hA, 128, 128, 1);
    // offconv3 (32->64) fused with deform: hA -> dC
    conv_s1_mfma<32, 64, 8, 1><<<dim3(4, 4, 16), 512, 0, stream>>>(hA, owt3, nullptr, dC, 64, 64, 0);

    // L4: conv4 (32->32, s2) 64->32
    conv_s2_mfma<32, 32, 4><<<dim3(4, 4, 16), 256, 0, stream>>>(dC, wt4, b4, hA, 64, 64, 1);
    avgpool_nhwc<<<16, 256, 0, stream>>>(hA, out);
}

// Round 6
// 559.322 us; speedup vs baseline: 1.0916x; 1.0916x over previous
//
#include <hip/hip_runtime.h>

typedef short short8 __attribute__((ext_vector_type(8)));
typedef float f32x4 __attribute__((ext_vector_type(4)));

__device__ __forceinline__ unsigned short f2b(float f) {
    unsigned u = __float_as_uint(f);
    u += 0x7fffu + ((u >> 16) & 1u);          // round-to-nearest-even
    return (unsigned short)(u >> 16);
}
__device__ __forceinline__ float b2f(unsigned short h) {
    return __uint_as_float(((unsigned)h) << 16);
}

// ---------------------------------------------------------------------------
// 3x3 conv, pad 1, stride 1, NHWC bf16, bf16 MFMA fp32 accum.
// Block: 16x16 output pixels x (NW/4) co-blocks of 32 c_out. NW waves.
// DEFORM=1: conv output = offsets (kept in s_off, never stored). Offsets are
// tiny (|off| << 1), so each sample's 4 bilinear taps live in the 10x10
// neighborhood of its identity position. The 4 neighborhoods (2 row-halves x
// 2 col-halves, 10x10 px x 32 ch) are staged into LDS with an 80B pixel
// stride (20 dwords -> 8 distinct bank-group starts; cross-half-wave tap
// reads drop from 4-way to ~2-way conflicts). Taps are ds_read_u16 with an
// exec-masked global fallback for the rare |off| >= 1.
// ---------------------------------------------------------------------------
template <int C_IN, int C_OUT, int NW, int DEFORM>
__global__ __launch_bounds__(NW * 64) void conv_s1_mfma(
    const unsigned short* __restrict__ in, const unsigned short* __restrict__ wT,
    const float* __restrict__ bias, unsigned short* __restrict__ out,
    int H, int W, int relu)
{
    constexpr int LDSTR  = C_IN + 8;
    constexpr int KSTEPS = C_IN / 32;
    constexpr int CH8    = C_IN / 8;
    constexpr int COPB   = 32 * (NW / 4);
    static_assert(!DEFORM || COPB == 64, "deform fusion expects 64 conv ch/block");
    constexpr int SSTR   = 40;                          // sample-buffer pixel stride
    constexpr int S_CONV = 18 * 18 * LDSTR;
    constexpr int S_SMP  = DEFORM ? 4 * 100 * SSTR : 0; // 16000 ush = 32 KB
    constexpr int S_A    = (S_CONV > S_SMP) ? S_CONV : S_SMP;
    __shared__ __align__(16) unsigned short s_in[S_A];
    __shared__ __align__(16) unsigned short s_off[DEFORM ? 16 * 16 * 64 : 8];

    const int tid   = threadIdx.x;
    const int wave  = tid >> 6;
    const int wv    = wave & 3;
    const int csub  = wave >> 2;
    const int lane  = tid & 63;
    const int mlane = lane & 15;
    const int quad  = lane >> 4;

    const int nCo  = C_OUT / COPB;
    const int b    = blockIdx.z / nCo;
    const int coB  = (blockIdx.z - b * nCo) * COPB + csub * 32;
    const int row0 = blockIdx.y * 16;
    const int col0 = blockIdx.x * 16;

    for (int idx = tid; idx < 18 * 18 * CH8; idx += NW * 64) {
        int pixel = idx / CH8;
        int ch    = (idx - pixel * CH8) * 8;
        int pr    = pixel / 18;
        int pc    = pixel - pr * 18;
        int gr = row0 - 1 + pr, gc = col0 - 1 + pc;
        ulonglong2 v; v.x = 0; v.y = 0;
        if ((unsigned)gr < (unsigned)H && (unsigned)gc < (unsigned)W)
            v = *(const ulonglong2*)&in[((b * H + gr) * W + gc) * C_IN + ch];
        *(ulonglong2*)&s_in[pixel * LDSTR + ch] = v;
    }
    __syncthreads();

    f32x4 acc[2][4];
    #pragma unroll
    for (int mt = 0; mt < 2; ++mt)
        #pragma unroll
        for (int t = 0; t < 4; ++t) acc[mt][t] = (f32x4)(0.f);

    #pragma unroll 1
    for (int kk = 0; kk < KSTEPS; ++kk) {
        short8 A[2][9];
        #pragma unroll
        for (int mt = 0; mt < 2; ++mt)
            #pragma unroll
            for (int tap = 0; tap < 9; ++tap)
                A[mt][tap] = *(const short8*)&wT[(tap * C_OUT + coB + mt * 16 + mlane) * C_IN
                                                 + kk * 32 + quad * 8];

        const unsigned short* sb =
            &s_in[(wv * 4 * 18 + mlane) * LDSTR + kk * 32 + quad * 8];
        #pragma unroll
        for (int t = 0; t < 4; ++t) {
            #pragma unroll
            for (int tap = 0; tap < 9; ++tap) {
                const int dy = tap / 3, dx = tap % 3;
                short8 Bf = *(const short8*)&sb[((t + dy) * 18 + dx) * LDSTR];
                acc[0][t] = __builtin_amdgcn_mfma_f32_16x16x32_bf16(A[0][tap], Bf, acc[0][t], 0, 0, 0);
                acc[1][t] = __builtin_amdgcn_mfma_f32_16x16x32_bf16(A[1][tap], Bf, acc[1][t], 0, 0, 0);
            }
        }
    }

    if (!DEFORM) {
        #pragma unroll
        for (int mt = 0; mt < 2; ++mt) {
            const int cb = coB + mt * 16 + quad * 4;
            float4 bv;
            if (bias) bv = *(const float4*)&bias[cb]; else { bv.x = bv.y = bv.z = bv.w = 0.f; }
            #pragma unroll
            for (int t = 0; t < 4; ++t) {
                const int row = row0 + wv * 4 + t, col = col0 + mlane;
                float o0 = acc[mt][t][0] + bv.x, o1 = acc[mt][t][1] + bv.y;
                float o2 = acc[mt][t][2] + bv.z, o3 = acc[mt][t][3] + bv.w;
                if (relu) {
                    o0 = fmaxf(o0, 0.f); o1 = fmaxf(o1, 0.f);
                    o2 = fmaxf(o2, 0.f); o3 = fmaxf(o3, 0.f);
                }
                ushort4 pk; pk.x = f2b(o0); pk.y = f2b(o1); pk.z = f2b(o2); pk.w = f2b(o3);
                *(ushort4*)&out[((b * H + row) * W + col) * C_OUT + cb] = pk;
            }
        }
    } else {
        const int zb    = blockIdx.z - b * nCo;
        const int zbase = zb * 32;
        const int Hh = H >> 1, Wh = W >> 1;
        const int r8 = blockIdx.y * 8, c8 = blockIdx.x * 8;

        __syncthreads();   // conv reads of s_in complete; s_in reused below

        // ---- phase A: offsets (bf16) -> s_off [16 row][16 col][64 ch], ch-XOR swizzled
        #pragma unroll
        for (int mt = 0; mt < 2; ++mt) {
            const int cb  = csub * 32 + mt * 16 + quad * 4;          // block-local ch
            const int swc = cb ^ ((mlane & 7) << 3);
            #pragma unroll
            for (int t = 0; t < 4; ++t) {
                ushort4 pk;
                pk.x = f2b(acc[mt][t][0]); pk.y = f2b(acc[mt][t][1]);
                pk.z = f2b(acc[mt][t][2]); pk.w = f2b(acc[mt][t][3]);
                *(ushort4*)&s_off[((wv * 4 + t) * 16 + mlane) * 64 + swc] = pk;
            }
        }

        // ---- stage 4 sample neighborhoods (10x10 px x 32 ch) into s_in
        // region reg = ih*2+chf: base (R0,C0) = (r8+ih*Hh, c8+chf*Wh), rows/cols
        // R0-1..R0+8 clamped to image. Layout: [reg][10r][10c][SSTR].
        for (int idx = tid; idx < 1600; idx += NW * 64) {
            const int pixel = idx >> 2;
            const int chq   = (idx & 3) * 8;
            const int reg   = pixel / 100;
            const int rem   = pixel - reg * 100;
            const int rr_   = rem / 10;
            const int cc_   = rem - rr_ * 10;
            int gr = r8 + (reg >> 1) * Hh - 1 + rr_;
            int gc = c8 + (reg & 1)  * Wh - 1 + cc_;
            gr = gr < 0 ? 0 : (gr > H - 1 ? H - 1 : gr);
            gc = gc < 0 ? 0 : (gc > W - 1 ? W - 1 : gc);
            *(ulonglong2*)&s_in[pixel * SSTR + chq] =
                *(const ulonglong2*)&in[((b * H + gr) * W + gc) * C_IN + zbase + chq];
        }
        __syncthreads();

        // ---- phase B: bilinear sampling from LDS neighborhoods
        const int ci   = tid & 31;          // sample channel (within this co-block)
        const int slot = tid >> 5;          // 0..15 position slot
        const unsigned short* xb = in  + (long)b * H * W * C_IN + zbase + ci;
        unsigned short*       ob = out + (long)b * H * W * C_IN + zbase + ci;
        const float Hm1 = (float)(H - 1), Wm1 = (float)(W - 1);

        #pragma unroll 4
        for (int s = 0; s < 8; ++s) {
            const int pos = slot + s * 16;          // 0..127
            const int rl  = pos >> 4;               // 0..7 sample row in tile
            const int cl  = (pos >> 1) & 7;         // 0..7 sample col in tile
            const int chf = pos & 1;                // col-half select
            const int lr  = rl * 2 + chf;           // conv-local row
            const int lc  = cl * 2;                 // conv-local col (even)
            const int bix = (lr * 16 + lc) * 64;
            const ushort2 roP = *(const ushort2*)&s_off[bix +      ((2 * ci) ^ ((lc & 7) << 3))];
            const ushort2 coP = *(const ushort2*)&s_off[bix + 64 + ((2 * ci) ^ (((lc + 1) & 7) << 3))];
            #pragma unroll
            for (int ih = 0; ih < 2; ++ih) {
                const int R0 = r8 + ih * Hh, C0 = c8 + chf * Wh;
                const int rowg = R0 + rl, cg = C0 + cl;
                const float rr = fminf(fmaxf(b2f(ih ? roP.y : roP.x) + (float)rowg, 0.f), Hm1);
                const float cc = fminf(fmaxf(b2f(ih ? coP.y : coP.x) + (float)cg,   0.f), Wm1);
                const float rf = floorf(rr), cf = floorf(cc);
                const float fr = rr - rf, fc = cc - cf;
                const int irf = (int)rf, icf = (int)cf;
                const int dr1 = (fr > 0.f) ? 1 : 0;
                const int dc1 = (fc > 0.f) ? 1 : 0;
                const int lr0 = irf - R0 + 1;       // LDS row 0..9 when in-box
                const int lc0 = icf - C0 + 1;
                float v00, v01, v10, v11;
                if ((unsigned)lr0 <= (unsigned)(9 - dr1) &&
                    (unsigned)lc0 <= (unsigned)(9 - dc1)) {
                    const int reg = ih * 2 + chf;
                    const unsigned short* sp =
                        &s_in[(reg * 100 + lr0 * 10 + lc0) * SSTR + ci];
                    v00 = b2f(sp[0]);
                    v01 = b2f(sp[dc1 * SSTR]);
                    v10 = b2f(sp[dr1 * 10 * SSTR]);
                    v11 = b2f(sp[dr1 * 10 * SSTR + dc1 * SSTR]);
                } else {                             // rare: |off| >= 1
                    const int idx00 = (irf * W + icf) * C_IN;
                    const int dr = dr1 * W * C_IN, dc = dc1 * C_IN;
                    v00 = b2f(xb[idx00]);
                    v01 = b2f(xb[idx00 + dc]);
                    v10 = b2f(xb[idx00 + dr]);
                    v11 = b2f(xb[idx00 + dr + dc]);
                }
                const float vt = v00 + (v10 - v00) * fr;
                const float vb = v01 + (v11 - v01) * fr;
                const float rs = vt + (vb - vt) * fc;
                ob[(rowg * W + cg) * C_IN] = f2b(rs);
            }
        }
    }
}

// ---------------------------------------------------------------------------
// 3x3 conv, pad 1, stride 2, NHWC bf16. Block: 8x8 out px x (NW/4) co-blocks.
// ---------------------------------------------------------------------------
template <int C_IN, int C_OUT, int NW>
__global__ __launch_bounds__(NW * 64) void conv_s2_mfma(
    const unsigned short* __restrict__ in, const unsigned short* __restrict__ wT,
    const float* __restrict__ bias, unsigned short* __restrict__ out,
    int H_in, int W_in, int relu)
{
    constexpr int LDSTR  = C_IN + 8;
    constexpr int KSTEPS = C_IN / 32;
    constexpr int CH8    = C_IN / 8;
    constexpr int COPB   = 32 * (NW / 4);
    __shared__ unsigned short s_in[17 * 17 * LDSTR];

    const int tid   = threadIdx.x;
    const int wave  = tid >> 6;
    const int wv    = wave & 3;
    const int csub  = wave >> 2;
    const int lane  = tid & 63;
    const int mlane = lane & 15;
    const int quad  = lane >> 4;

    const int H_out = H_in >> 1, W_out = W_in >> 1;
    const int nCo   = C_OUT / COPB;
    const int b     = blockIdx.z / nCo;
    const int coB   = (blockIdx.z - b * nCo) * COPB + csub * 32;
    const int orow0 = blockIdx.y * 8, ocol0 = blockIdx.x * 8;
    const int irow0 = orow0 * 2 - 1,  icol0 = ocol0 * 2 - 1;

    for (int idx = tid; idx < 17 * 17 * CH8; idx += NW * 64) {
        int pixel = idx / CH8;
        int ch    = (idx - pixel * CH8) * 8;
        int pr    = pixel / 17;
        int pc    = pixel - pr * 17;
        int gr = irow0 + pr, gc = icol0 + pc;
        ulonglong2 v; v.x = 0; v.y = 0;
        if ((unsigned)gr < (unsigned)H_in && (unsigned)gc < (unsigned)W_in)
            v = *(const ulonglong2*)&in[((b * H_in + gr) * W_in + gc) * C_IN + ch];
        *(ulonglong2*)&s_in[pixel * LDSTR + ch] = v;
    }
    __syncthreads();

    f32x4 acc[2];
    acc[0] = (f32x4)(0.f); acc[1] = (f32x4)(0.f);

    const int plr = wv * 2 + (mlane >> 3);
    const int plc = mlane & 7;

    #pragma unroll 1
    for (int kk = 0; kk < KSTEPS; ++kk) {
        short8 A[2][9];
        #pragma unroll
        for (int mt = 0; mt < 2; ++mt)
            #pragma unroll
            for (int tap = 0; tap < 9; ++tap)
                A[mt][tap] = *(const short8*)&wT[(tap * C_OUT + coB + mt * 16 + mlane) * C_IN
                                                 + kk * 32 + quad * 8];

        const unsigned short* sb0 =
            &s_in[(plr * 2 * 17 + plc * 2) * LDSTR + kk * 32 + quad * 8];
        #pragma unroll
        for (int tap = 0; tap < 9; ++tap) {
            const int dy = tap / 3, dx = tap % 3;
            short8 Bf = *(const short8*)&sb0[(dy * 17 + dx) * LDSTR];
            acc[0] = __builtin_amdgcn_mfma_f32_16x16x32_bf16(A[0][tap], Bf, acc[0], 0, 0, 0);
            acc[1] = __builtin_amdgcn_mfma_f32_16x16x32_bf16(A[1][tap], Bf, acc[1], 0, 0, 0);
        }
    }

    const int row = orow0 + plr, col = ocol0 + plc;
    #pragma unroll
    for (int mt = 0; mt < 2; ++mt) {
        const int cb = coB + mt * 16 + quad * 4;
        float4 bv;
        if (bias) bv = *(const float4*)&bias[cb]; else { bv.x = bv.y = bv.z = bv.w = 0.f; }
        float o0 = acc[mt][0] + bv.x, o1 = acc[mt][1] + bv.y;
        float o2 = acc[mt][2] + bv.z, o3 = acc[mt][3] + bv.w;
        if (relu) {
            o0 = fmaxf(o0, 0.f); o1 = fmaxf(o1, 0.f);
            o2 = fmaxf(o2, 0.f); o3 = fmaxf(o3, 0.f);
        }
        ushort4 pk; pk.x = f2b(o0); pk.y = f2b(o1); pk.z = f2b(o2); pk.w = f2b(o3);
        *(ushort4*)&out[((b * H_out + row) * W_out + col) * C_OUT + cb] = pk;
    }
}

// ---------------------------------------------------------------------------
// x: fp32 NCHW (C=32) -> bf16 NHWC via LDS transpose. Block: 32ch x 64 px.
// ---------------------------------------------------------------------------
__global__ __launch_bounds__(256) void nchw2nhwc(
    const float* __restrict__ x, unsigned short* __restrict__ out, int HW)
{
    __shared__ float s[32][65];
    const int b = blockIdx.y, p0 = blockIdx.x * 64;
    const int tid = threadIdx.x;
    #pragma unroll
    for (int k = 0; k < 8; ++k) {
        int e = tid + k * 256, ci = e >> 6, p = e & 63;
        s[ci][p] = x[(b * 32 + ci) * HW + p0 + p];
    }
    __syncthreads();
    #pragma unroll
    for (int k = 0; k < 8; ++k) {
        int e = tid + k * 256, p = e >> 5, ci = e & 31;
        out[(b * HW + p0 + p) * 32 + ci] = f2b(s[ci][p]);
    }
}

// all 7 weight transforms in one launch: fp32 OIHW -> bf16 [tap][C_out][C_in]
struct WTArgs {
    const float* src[7];
    unsigned short* dst[7];
    int co[7], ci[7], n[7];
};
__global__ __launch_bounds__(256) void wtrans_all(WTArgs a)
{
    const int i = blockIdx.x * 256 + threadIdx.x;
    #pragma unroll
    for (int s = 0; s < 7; ++s) {
        if (i < a.n[s]) {
            const int ci  = i % a.ci[s];
            const int rr  = i / a.ci[s];
            const int co  = rr % a.co[s];
            const int tap = rr / a.co[s];
            a.dst[s][i] = f2b(a.src[s][(co * a.ci[s] + ci) * 9 + tap]);
        }
    }
}

// global avg pool over 32x32, NHWC bf16 (C=32) -> fp32 (B,C)
__global__ __launch_bounds__(256) void avgpool_nhwc(
    const unsigned short* __restrict__ in, float* __restrict__ out)
{
    const int b = blockIdx.x, tid = threadIdx.x;
    const int ci = tid & 31, pg = tid >> 5;
    float s = 0.f;
    for (int k = 0; k < 128; ++k) {
        int p = pg * 128 + k;
        s += b2f(in[(b * 1024 + p) * 32 + ci]);
    }
    __shared__ float red[8][32];
    red[pg][ci] = s;
    __syncthreads();
    if (tid < 32) {
        float t = 0.f;
        #pragma unroll
        for (int j = 0; j < 8; ++j) t += red[j][tid];
        out[b * 32 + tid] = t * (1.f / 1024.f);
    }
}

__global__ __launch_bounds__(256) void sentinel(float* out, int n, float v)
{
    int i = blockIdx.x * 256 + threadIdx.x;
    if (i < n) out[i] = v;
}

extern "C" void kernel_launch(void* const* d_in, const int* in_sizes, int n_in,
                              void* d_out, int out_size, void* d_ws, size_t ws_size,
                              hipStream_t stream) {
    (void)in_sizes; (void)n_in; (void)out_size;
    const float* x   = (const float*)d_in[0];
    const float* w1  = (const float*)d_in[1];
    const float* b1  = (const float*)d_in[2];
    const float* ow1 = (const float*)d_in[3];
    const float* w2  = (const float*)d_in[4];
    const float* b2  = (const float*)d_in[5];
    const float* ow2 = (const float*)d_in[6];
    const float* w3  = (const float*)d_in[7];
    const float* b3  = (const float*)d_in[8];
    const float* ow3 = (const float*)d_in[9];
    const float* w4  = (const float*)d_in[10];
    const float* b4  = (const float*)d_in[11];
    float* out = (float*)d_out;
    unsigned short* wsu = (unsigned short*)d_ws;

    const size_t XB = 0;
    const size_t HA = 33554432;
    const size_t DC = 134217728;
    const size_t WB = 167772160;
    const size_t total_us = WB + 165888;
    if (ws_size < total_us * 2) {
        sentinel<<<2, 256, 0, stream>>>(out, 512, 12345.0f);
        return;
    }
    unsigned short* xb = wsu + XB;
    unsigned short* hA = wsu + HA;
    unsigned short* dC = wsu + DC;
    unsigned short* wt1  = wsu + WB;
    unsigned short* owt1 = wt1 + 9216;
    unsigned short* wt2  = owt1 + 18432;
    unsigned short* owt2 = wt2 + 18432;
    unsigned short* wt3  = owt2 + 73728;
    unsigned short* owt3 = wt3 + 18432;
    unsigned short* wt4  = owt3 + 18432;

    WTArgs wa;
    wa.src[0] = w1;  wa.dst[0] = wt1;  wa.co[0] = 32;  wa.ci[0] = 32; wa.n[0] = 9216;
    wa.src[1] = ow1; wa.dst[1] = owt1; wa.co[1] = 64;  wa.ci[1] = 32; wa.n[1] = 18432;
    wa.src[2] = w2;  wa.dst[2] = wt2;  wa.co[2] = 64;  wa.ci[2] = 32; wa.n[2] = 18432;
    wa.src[3] = ow2; wa.dst[3] = owt2; wa.co[3] = 128; wa.ci[3] = 64; wa.n[3] = 73728;
    wa.src[4] = w3;  wa.dst[4] = wt3;  wa.co[4] = 32;  wa.ci[4] = 64; wa.n[4] = 18432;
    wa.src[5] = ow3; wa.dst[5] = owt3; wa.co[5] = 64;  wa.ci[5] = 32; wa.n[5] = 18432;
    wa.src[6] = w4;  wa.dst[6] = wt4;  wa.co[6] = 32;  wa.ci[6] = 32; wa.n[6] = 9216;
    wtrans_all<<<288, 256, 0, stream>>>(wa);

    nchw2nhwc<<<dim3(1024, 16), 256, 0, stream>>>(x, xb, 65536);

    // L1: conv1 (32->32, 256x256, s1, relu)
    conv_s1_mfma<32, 32, 4, 0><<<dim3(16, 16, 16), 256, 0, stream>>>(xb, wt1, b1, hA, 256, 256, 1);
    // offconv1 (32->64) fused with deformable sampling: hA -> dC
    conv_s1_mfma<32, 64, 8, 1><<<dim3(16, 16, 16), 512, 0, stream>>>(hA, owt1, nullptr, dC, 256, 256, 0);

    // L2: conv2 (32->64, s2) 256->128
    conv_s2_mfma<32, 64, 8><<<dim3(16, 16, 16), 512, 0, stream>>>(dC, wt2, b2, hA, 256, 256, 1);
    // offconv2 (64->128) fused with deform: hA -> dC
    conv_s1_mfma<64, 128, 8, 1><<<dim3(8, 8, 32), 512, 0, stream>>>(hA, owt2, nullptr, dC, 128, 128, 0);

    // L3: conv3 (64->32, s2) 128->64
    conv_s2_mfma<64, 32, 4><<<dim3(8, 8, 16), 256, 0, stream>>>(dC, wt3, b3, hA, 128, 128, 1);
    // offconv3 (32->64) fused with deform: hA -> dC
    conv_s1_mfma<32, 64, 8, 1><<<dim3(4, 4, 16), 512, 0, stream>>>(hA, owt3, nullptr, dC, 64, 64, 0);

    // L4: conv4 (32->32, s2) 64->32
    conv_s2_mfma<32, 32, 4><<<dim3(4, 4, 16), 256, 0, stream>>>(dC, wt4, b4, hA, 64, 64, 1);
    avgpool_nhwc<<<16, 256, 0, stream>>>(hA, out);
}

// Round 7
// 550.038 us; speedup vs baseline: 1.1101x; 1.0169x over previous
//
#include <hip/hip_runtime.h>

typedef short short8 __attribute__((ext_vector_type(8)));
typedef float f32x4 __attribute__((ext_vector_type(4)));

__device__ __forceinline__ unsigned short f2b(float f) {
    unsigned u = __float_as_uint(f);
    u += 0x7fffu + ((u >> 16) & 1u);          // round-to-nearest-even
    return (unsigned short)(u >> 16);
}
__device__ __forceinline__ float b2f(unsigned short h) {
    return __uint_as_float(((unsigned)h) << 16);
}

// ---------------------------------------------------------------------------
// 3x3 conv, pad 1, stride 1, NHWC bf16, bf16 MFMA fp32 accum.
// Block: 16x16 output pixels x (NW/4) co-blocks of 32 c_out. NW waves.
// DEFORM=1: conv output = offsets (kept in s_off, never stored). Offsets are
// tiny (|off| << 1), so each sample's 4 bilinear taps live in the 10x10
// neighborhood of its identity position; neighborhoods staged in LDS
// ([reg][10r][10c][SSTR=40]). Phase-B VALU is minimized: med3 clamps,
// trunc-as-floor, and an UNCONDITIONAL 4-tap read (v+(v'-v)*0==v exactly,
// clamp-duplicated border rows keep it exact) so the 4 ds_read_u16 share one
// base + immediate offsets. Exec-masked global fallback for |off| >= 1.
// ---------------------------------------------------------------------------
template <int C_IN, int C_OUT, int NW, int DEFORM>
__global__ __launch_bounds__(NW * 64) void conv_s1_mfma(
    const unsigned short* __restrict__ in, const unsigned short* __restrict__ wT,
    const float* __restrict__ bias, unsigned short* __restrict__ out,
    int H, int W, int relu)
{
    constexpr int LDSTR  = C_IN + 8;
    constexpr int KSTEPS = C_IN / 32;
    constexpr int CH8    = C_IN / 8;
    constexpr int COPB   = 32 * (NW / 4);
    static_assert(!DEFORM || COPB == 64, "deform fusion expects 64 conv ch/block");
    constexpr int SSTR   = 40;                          // sample-buffer pixel stride
    constexpr int S_CONV = 18 * 18 * LDSTR;
    constexpr int S_SMP  = DEFORM ? 4 * 100 * SSTR : 0; // 16000 ush = 32 KB
    constexpr int S_A    = (S_CONV > S_SMP) ? S_CONV : S_SMP;
    __shared__ __align__(16) unsigned short s_in[S_A];
    __shared__ __align__(16) unsigned short s_off[DEFORM ? 16 * 16 * 64 : 8];

    const int tid   = threadIdx.x;
    const int wave  = tid >> 6;
    const int wv    = wave & 3;
    const int csub  = wave >> 2;
    const int lane  = tid & 63;
    const int mlane = lane & 15;
    const int quad  = lane >> 4;

    const int nCo  = C_OUT / COPB;
    const int b    = blockIdx.z / nCo;
    const int coB  = (blockIdx.z - b * nCo) * COPB + csub * 32;
    const int row0 = blockIdx.y * 16;
    const int col0 = blockIdx.x * 16;

    for (int idx = tid; idx < 18 * 18 * CH8; idx += NW * 64) {
        int pixel = idx / CH8;
        int ch    = (idx - pixel * CH8) * 8;
        int pr    = pixel / 18;
        int pc    = pixel - pr * 18;
        int gr = row0 - 1 + pr, gc = col0 - 1 + pc;
        ulonglong2 v; v.x = 0; v.y = 0;
        if ((unsigned)gr < (unsigned)H && (unsigned)gc < (unsigned)W)
            v = *(const ulonglong2*)&in[((b * H + gr) * W + gc) * C_IN + ch];
        *(ulonglong2*)&s_in[pixel * LDSTR + ch] = v;
    }
    __syncthreads();

    f32x4 acc[2][4];
    #pragma unroll
    for (int mt = 0; mt < 2; ++mt)
        #pragma unroll
        for (int t = 0; t < 4; ++t) acc[mt][t] = (f32x4)(0.f);

    #pragma unroll 1
    for (int kk = 0; kk < KSTEPS; ++kk) {
        short8 A[2][9];
        #pragma unroll
        for (int mt = 0; mt < 2; ++mt)
            #pragma unroll
            for (int tap = 0; tap < 9; ++tap)
                A[mt][tap] = *(const short8*)&wT[(tap * C_OUT + coB + mt * 16 + mlane) * C_IN
                                                 + kk * 32 + quad * 8];

        const unsigned short* sb =
            &s_in[(wv * 4 * 18 + mlane) * LDSTR + kk * 32 + quad * 8];
        #pragma unroll
        for (int t = 0; t < 4; ++t) {
            #pragma unroll
            for (int tap = 0; tap < 9; ++tap) {
                const int dy = tap / 3, dx = tap % 3;
                short8 Bf = *(const short8*)&sb[((t + dy) * 18 + dx) * LDSTR];
                acc[0][t] = __builtin_amdgcn_mfma_f32_16x16x32_bf16(A[0][tap], Bf, acc[0][t], 0, 0, 0);
                acc[1][t] = __builtin_amdgcn_mfma_f32_16x16x32_bf16(A[1][tap], Bf, acc[1][t], 0, 0, 0);
            }
        }
    }

    if (!DEFORM) {
        #pragma unroll
        for (int mt = 0; mt < 2; ++mt) {
            const int cb = coB + mt * 16 + quad * 4;
            float4 bv;
            if (bias) bv = *(const float4*)&bias[cb]; else { bv.x = bv.y = bv.z = bv.w = 0.f; }
            #pragma unroll
            for (int t = 0; t < 4; ++t) {
                const int row = row0 + wv * 4 + t, col = col0 + mlane;
                float o0 = acc[mt][t][0] + bv.x, o1 = acc[mt][t][1] + bv.y;
                float o2 = acc[mt][t][2] + bv.z, o3 = acc[mt][t][3] + bv.w;
                if (relu) {
                    o0 = fmaxf(o0, 0.f); o1 = fmaxf(o1, 0.f);
                    o2 = fmaxf(o2, 0.f); o3 = fmaxf(o3, 0.f);
                }
                ushort4 pk; pk.x = f2b(o0); pk.y = f2b(o1); pk.z = f2b(o2); pk.w = f2b(o3);
                *(ushort4*)&out[((b * H + row) * W + col) * C_OUT + cb] = pk;
            }
        }
    } else {
        const int zb    = blockIdx.z - b * nCo;
        const int zbase = zb * 32;
        const int Hh = H >> 1, Wh = W >> 1;
        const int r8 = blockIdx.y * 8, c8 = blockIdx.x * 8;

        __syncthreads();   // conv reads of s_in complete; s_in reused below

        // ---- phase A: offsets (bf16) -> s_off [16 row][16 col][64 ch], ch-XOR swizzled
        #pragma unroll
        for (int mt = 0; mt < 2; ++mt) {
            const int cb  = csub * 32 + mt * 16 + quad * 4;          // block-local ch
            const int swc = cb ^ ((mlane & 7) << 3);
            #pragma unroll
            for (int t = 0; t < 4; ++t) {
                ushort4 pk;
                pk.x = f2b(acc[mt][t][0]); pk.y = f2b(acc[mt][t][1]);
                pk.z = f2b(acc[mt][t][2]); pk.w = f2b(acc[mt][t][3]);
                *(ushort4*)&s_off[((wv * 4 + t) * 16 + mlane) * 64 + swc] = pk;
            }
        }

        // ---- stage 4 sample neighborhoods (10x10 px x 32 ch) into s_in
        // region reg = ih*2+chf: base (R0,C0) = (r8+ih*Hh, c8+chf*Wh), rows/cols
        // R0-1..R0+8 clamped to image. Layout: [reg][10r][10c][SSTR].
        for (int idx = tid; idx < 1600; idx += NW * 64) {
            const int pixel = idx >> 2;
            const int chq   = (idx & 3) * 8;
            const int reg   = pixel / 100;
            const int rem   = pixel - reg * 100;
            const int rr_   = rem / 10;
            const int cc_   = rem - rr_ * 10;
            int gr = r8 + (reg >> 1) * Hh - 1 + rr_;
            int gc = c8 + (reg & 1)  * Wh - 1 + cc_;
            gr = gr < 0 ? 0 : (gr > H - 1 ? H - 1 : gr);
            gc = gc < 0 ? 0 : (gc > W - 1 ? W - 1 : gc);
            *(ulonglong2*)&s_in[pixel * SSTR + chq] =
                *(const ulonglong2*)&in[((b * H + gr) * W + gc) * C_IN + zbase + chq];
        }
        __syncthreads();

        // ---- phase B: bilinear sampling from LDS neighborhoods
        const int ci   = tid & 31;          // sample channel (within this co-block)
        const int slot = tid >> 5;          // 0..15 position slot
        const unsigned short* xb = in  + (long)b * H * W * C_IN + zbase + ci;
        unsigned short*       ob = out + (long)b * H * W * C_IN + zbase + ci;
        const float Hm1 = (float)(H - 1), Wm1 = (float)(W - 1);

        #pragma unroll 4
        for (int s = 0; s < 8; ++s) {
            const int pos = slot + s * 16;          // 0..127
            const int rl  = pos >> 4;               // 0..7 sample row in tile
            const int cl  = (pos >> 1) & 7;         // 0..7 sample col in tile
            const int chf = pos & 1;                // col-half select
            const int lr  = rl * 2 + chf;           // conv-local row
            const int lc  = cl * 2;                 // conv-local col (even)
            const int bix = (lr * 16 + lc) * 64;
            const ushort2 roP = *(const ushort2*)&s_off[bix +      ((2 * ci) ^ ((lc & 7) << 3))];
            const ushort2 coP = *(const ushort2*)&s_off[bix + 64 + ((2 * ci) ^ (((lc + 1) & 7) << 3))];
            #pragma unroll
            for (int ih = 0; ih < 2; ++ih) {
                const int R0 = r8 + ih * Hh, C0 = c8 + chf * Wh;
                const int rowg = R0 + rl, cg = C0 + cl;
                const float rr = __builtin_amdgcn_fmed3f(
                    b2f(ih ? roP.y : roP.x) + (float)rowg, 0.f, Hm1);
                const float cc = __builtin_amdgcn_fmed3f(
                    b2f(ih ? coP.y : coP.x) + (float)cg, 0.f, Wm1);
                const int irf = (int)rr, icf = (int)cc;   // rr,cc >= 0: trunc == floor
                const float fr = rr - (float)irf;
                const float fc = cc - (float)icf;
                const int lr0 = irf - R0 + 1;       // LDS row 0..9 when in-box
                const int lc0 = icf - C0 + 1;
                float v00, v01, v10, v11;
                if ((unsigned)lr0 <= 8u && (unsigned)lc0 <= 8u) {
                    // unconditional 4-tap: shared base, immediate offsets
                    const unsigned short* sp =
                        &s_in[((ih * 2 + chf) * 100 + lr0 * 10 + lc0) * SSTR + ci];
                    v00 = b2f(sp[0]);
                    v01 = b2f(sp[SSTR]);
                    v10 = b2f(sp[10 * SSTR]);
                    v11 = b2f(sp[11 * SSTR]);
                } else {                             // rare: |off| >= 1
                    const int dr1 = (fr > 0.f) ? 1 : 0;
                    const int dc1 = (fc > 0.f) ? 1 : 0;
                    const int idx00 = (irf * W + icf) * C_IN;
                    const int dr = dr1 * W * C_IN, dc = dc1 * C_IN;
                    v00 = b2f(xb[idx00]);
                    v01 = b2f(xb[idx00 + dc]);
                    v10 = b2f(xb[idx00 + dr]);
                    v11 = b2f(xb[idx00 + dr + dc]);
                }
                const float vt = v00 + (v10 - v00) * fr;
                const float vb = v01 + (v11 - v01) * fr;
                const float rs = vt + (vb - vt) * fc;
                ob[(rowg * W + cg) * C_IN] = f2b(rs);
            }
        }
    }
}

// ---------------------------------------------------------------------------
// 3x3 conv, pad 1, stride 2, NHWC bf16. Block: 8x8 out px x (NW/4) co-blocks.
// ---------------------------------------------------------------------------
template <int C_IN, int C_OUT, int NW>
__global__ __launch_bounds__(NW * 64) void conv_s2_mfma(
    const unsigned short* __restrict__ in, const unsigned short* __restrict__ wT,
    const float* __restrict__ bias, unsigned short* __restrict__ out,
    int H_in, int W_in, int relu)
{
    constexpr int LDSTR  = C_IN + 8;
    constexpr int KSTEPS = C_IN / 32;
    constexpr int CH8    = C_IN / 8;
    constexpr int COPB   = 32 * (NW / 4);
    __shared__ unsigned short s_in[17 * 17 * LDSTR];

    const int tid   = threadIdx.x;
    const int wave  = tid >> 6;
    const int wv    = wave & 3;
    const int csub  = wave >> 2;
    const int lane  = tid & 63;
    const int mlane = lane & 15;
    const int quad  = lane >> 4;

    const int H_out = H_in >> 1, W_out = W_in >> 1;
    const int nCo   = C_OUT / COPB;
    const int b     = blockIdx.z / nCo;
    const int coB   = (blockIdx.z - b * nCo) * COPB + csub * 32;
    const int orow0 = blockIdx.y * 8, ocol0 = blockIdx.x * 8;
    const int irow0 = orow0 * 2 - 1,  icol0 = ocol0 * 2 - 1;

    for (int idx = tid; idx < 17 * 17 * CH8; idx += NW * 64) {
        int pixel = idx / CH8;
        int ch    = (idx - pixel * CH8) * 8;
        int pr    = pixel / 17;
        int pc    = pixel - pr * 17;
        int gr = irow0 + pr, gc = icol0 + pc;
        ulonglong2 v; v.x = 0; v.y = 0;
        if ((unsigned)gr < (unsigned)H_in && (unsigned)gc < (unsigned)W_in)
            v = *(const ulonglong2*)&in[((b * H_in + gr) * W_in + gc) * C_IN + ch];
        *(ulonglong2*)&s_in[pixel * LDSTR + ch] = v;
    }
    __syncthreads();

    f32x4 acc[2];
    acc[0] = (f32x4)(0.f); acc[1] = (f32x4)(0.f);

    const int plr = wv * 2 + (mlane >> 3);
    const int plc = mlane & 7;

    #pragma unroll 1
    for (int kk = 0; kk < KSTEPS; ++kk) {
        short8 A[2][9];
        #pragma unroll
        for (int mt = 0; mt < 2; ++mt)
            #pragma unroll
            for (int tap = 0; tap < 9; ++tap)
                A[mt][tap] = *(const short8*)&wT[(tap * C_OUT + coB + mt * 16 + mlane) * C_IN
                                                 + kk * 32 + quad * 8];

        const unsigned short* sb0 =
            &s_in[(plr * 2 * 17 + plc * 2) * LDSTR + kk * 32 + quad * 8];
        #pragma unroll
        for (int tap = 0; tap < 9; ++tap) {
            const int dy = tap / 3, dx = tap % 3;
            short8 Bf = *(const short8*)&sb0[(dy * 17 + dx) * LDSTR];
            acc[0] = __builtin_amdgcn_mfma_f32_16x16x32_bf16(A[0][tap], Bf, acc[0], 0, 0, 0);
            acc[1] = __builtin_amdgcn_mfma_f32_16x16x32_bf16(A[1][tap], Bf, acc[1], 0, 0, 0);
        }
    }

    const int row = orow0 + plr, col = ocol0 + plc;
    #pragma unroll
    for (int mt = 0; mt < 2; ++mt) {
        const int cb = coB + mt * 16 + quad * 4;
        float4 bv;
        if (bias) bv = *(const float4*)&bias[cb]; else { bv.x = bv.y = bv.z = bv.w = 0.f; }
        float o0 = acc[mt][0] + bv.x, o1 = acc[mt][1] + bv.y;
        float o2 = acc[mt][2] + bv.z, o3 = acc[mt][3] + bv.w;
        if (relu) {
            o0 = fmaxf(o0, 0.f); o1 = fmaxf(o1, 0.f);
            o2 = fmaxf(o2, 0.f); o3 = fmaxf(o3, 0.f);
        }
        ushort4 pk; pk.x = f2b(o0); pk.y = f2b(o1); pk.z = f2b(o2); pk.w = f2b(o3);
        *(ushort4*)&out[((b * H_out + row) * W_out + col) * C_OUT + cb] = pk;
    }
}

// ---------------------------------------------------------------------------
// x: fp32 NCHW (C=32) -> bf16 NHWC via LDS transpose. Block: 32ch x 64 px.
// ---------------------------------------------------------------------------
__global__ __launch_bounds__(256) void nchw2nhwc(
    const float* __restrict__ x, unsigned short* __restrict__ out, int HW)
{
    __shared__ float s[32][65];
    const int b = blockIdx.y, p0 = blockIdx.x * 64;
    const int tid = threadIdx.x;
    #pragma unroll
    for (int k = 0; k < 8; ++k) {
        int e = tid + k * 256, ci = e >> 6, p = e & 63;
        s[ci][p] = x[(b * 32 + ci) * HW + p0 + p];
    }
    __syncthreads();
    #pragma unroll
    for (int k = 0; k < 8; ++k) {
        int e = tid + k * 256, p = e >> 5, ci = e & 31;
        out[(b * HW + p0 + p) * 32 + ci] = f2b(s[ci][p]);
    }
}

// all 7 weight transforms in one launch: fp32 OIHW -> bf16 [tap][C_out][C_in]
struct WTArgs {
    const float* src[7];
    unsigned short* dst[7];
    int co[7], ci[7], n[7];
};
__global__ __launch_bounds__(256) void wtrans_all(WTArgs a)
{
    const int i = blockIdx.x * 256 + threadIdx.x;
    #pragma unroll
    for (int s = 0; s < 7; ++s) {
        if (i < a.n[s]) {
            const int ci  = i % a.ci[s];
            const int rr  = i / a.ci[s];
            const int co  = rr % a.co[s];
            const int tap = rr / a.co[s];
            a.dst[s][i] = f2b(a.src[s][(co * a.ci[s] + ci) * 9 + tap]);
        }
    }
}

// global avg pool over 32x32, NHWC bf16 (C=32) -> fp32 (B,C)
__global__ __launch_bounds__(256) void avgpool_nhwc(
    const unsigned short* __restrict__ in, float* __restrict__ out)
{
    const int b = blockIdx.x, tid = threadIdx.x;
    const int ci = tid & 31, pg = tid >> 5;
    float s = 0.f;
    for (int k = 0; k < 128; ++k) {
        int p = pg * 128 + k;
        s += b2f(in[(b * 1024 + p) * 32 + ci]);
    }
    __shared__ float red[8][32];
    red[pg][ci] = s;
    __syncthreads();
    if (tid < 32) {
        float t = 0.f;
        #pragma unroll
        for (int j = 0; j < 8; ++j) t += red[j][tid];
        out[b * 32 + tid] = t * (1.f / 1024.f);
    }
}

__global__ __launch_bounds__(256) void sentinel(float* out, int n, float v)
{
    int i = blockIdx.x * 256 + threadIdx.x;
    if (i < n) out[i] = v;
}

extern "C" void kernel_launch(void* const* d_in, const int* in_sizes, int n_in,
                              void* d_out, int out_size, void* d_ws, size_t ws_size,
                              hipStream_t stream) {
    (void)in_sizes; (void)n_in; (void)out_size;
    const float* x   = (const float*)d_in[0];
    const float* w1  = (const float*)d_in[1];
    const float* b1  = (const float*)d_in[2];
    const float* ow1 = (const float*)d_in[3];
    const float* w2  = (const float*)d_in[4];
    const float* b2  = (const float*)d_in[5];
    const float* ow2 = (const float*)d_in[6];
    const float* w3  = (const float*)d_in[7];
    const float* b3  = (const float*)d_in[8];
    const float* ow3 = (const float*)d_in[9];
    const float* w4  = (const float*)d_in[10];
    const float* b4  = (const float*)d_in[11];
    float* out = (float*)d_out;
    unsigned short* wsu = (unsigned short*)d_ws;

    const size_t XB = 0;
    const size_t HA = 33554432;
    const size_t DC = 134217728;
    const size_t WB = 167772160;
    const size_t total_us = WB + 165888;
    if (ws_size < total_us * 2) {
        sentinel<<<2, 256, 0, stream>>>(out, 512, 12345.0f);
        return;
    }
    unsigned short* xb = wsu + XB;
    unsigned short* hA = wsu + HA;
    unsigned short* dC = wsu + DC;
    unsigned short* wt1  = wsu + WB;
    unsigned short* owt1 = wt1 + 9216;
    unsigned short* wt2  = owt1 + 18432;
    unsigned short* owt2 = wt2 + 18432;
    unsigned short* wt3  = owt2 + 73728;
    unsigned short* owt3 = wt3 + 18432;
    unsigned short* wt4  = owt3 + 18432;

    WTArgs wa;
    wa.src[0] = w1;  wa.dst[0] = wt1;  wa.co[0] = 32;  wa.ci[0] = 32; wa.n[0] = 9216;
    wa.src[1] = ow1; wa.dst[1] = owt1; wa.co[1] = 64;  wa.ci[1] = 32; wa.n[1] = 18432;
    wa.src[2] = w2;  wa.dst[2] = wt2;  wa.co[2] = 64;  wa.ci[2] = 32; wa.n[2] = 18432;
    wa.src[3] = ow2; wa.dst[3] = owt2; wa.co[3] = 128; wa.ci[3] = 64; wa.n[3] = 73728;
    wa.src[4] = w3;  wa.dst[4] = wt3;  wa.co[4] = 32;  wa.ci[4] = 64; wa.n[4] = 18432;
    wa.src[5] = ow3; wa.dst[5] = owt3; wa.co[5] = 64;  wa.ci[5] = 32; wa.n[5] = 18432;
    wa.src[6] = w4;  wa.dst[6] = wt4;  wa.co[6] = 32;  wa.ci[6] = 32; wa.n[6] = 9216;
    wtrans_all<<<288, 256, 0, stream>>>(wa);

    nchw2nhwc<<<dim3(1024, 16), 256, 0, stream>>>(x, xb, 65536);

    // L1: conv1 (32->32, 256x256, s1, relu)
    conv_s1_mfma<32, 32, 4, 0><<<dim3(16, 16, 16), 256, 0, stream>>>(xb, wt1, b1, hA, 256, 256, 1);
    // offconv1 (32->64) fused with deformable sampling: hA -> dC
    conv_s1_mfma<32, 64, 8, 1><<<dim3(16, 16, 16), 512, 0, stream>>>(hA, owt1, nullptr, dC, 256, 256, 0);

    // L2: conv2 (32->64, s2) 256->128
    conv_s2_mfma<32, 64, 8><<<dim3(16, 16, 16), 512, 0, stream>>>(dC, wt2, b2, hA, 256, 256, 1);
    // offconv2 (64->128) fused with deform: hA -> dC
    conv_s1_mfma<64, 128, 8, 1><<<dim3(8, 8, 32), 512, 0, stream>>>(hA, owt2, nullptr, dC, 128, 128, 0);

    // L3: conv3 (64->32, s2) 128->64
    conv_s2_mfma<64, 32, 4><<<dim3(8, 8, 16), 256, 0, stream>>>(dC, wt3, b3, hA, 128, 128, 1);
    // offconv3 (32->64) fused with deform: hA -> dC
    conv_s1_mfma<32, 64, 8, 1><<<dim3(4, 4, 16), 512, 0, stream>>>(hA, owt3, nullptr, dC, 64, 64, 0);

    // L4: conv4 (32->32, s2) 64->32
    conv_s2_mfma<32, 32, 4><<<dim3(4, 4, 16), 256, 0, stream>>>(dC, wt4, b4, hA, 64, 64, 1);
    avgpool_nhwc<<<16, 256, 0, stream>>>(hA, out);
}

// Round 9
// 500.969 us; speedup vs baseline: 1.2188x; 1.0979x over previous
//
#include <hip/hip_runtime.h>

typedef short short8 __attribute__((ext_vector_type(8)));
typedef float f32x4 __attribute__((ext_vector_type(4)));

__device__ __forceinline__ unsigned short f2b(float f) {
    unsigned u = __float_as_uint(f);
    u += 0x7fffu + ((u >> 16) & 1u);          // round-to-nearest-even
    return (unsigned short)(u >> 16);
}
__device__ __forceinline__ float b2f(unsigned short h) {
    return __uint_as_float(((unsigned)h) << 16);
}

// Weight layout: [tap][co/16][ci/8][co%16][8ci] -> a wave's A-fragment load is
// base + lane*16B (lane = quad*16+mlane), one fully-coalesced 1KB load.

// ---------------------------------------------------------------------------
// 3x3 conv, pad 1, stride 1, NHWC bf16, bf16 MFMA fp32 accum.
// Block: 16x16 output pixels x (NW/4) co-blocks of 32 c_out. NW waves.
// DEFORM=1: conv output = offsets (kept in s_off, never stored). Sample taps
// come from 4x(10x10x32ch) LDS neighborhoods (SSTR=40 pixel stride), staged
// T14-style: global loads issued into regs BEFORE the conv barrier (latency
// absorbed by the staging drain), ds_written in phase A. Unconditional 4-tap
// LDS read (v+(v'-v)*0==v, clamp-duplicated borders keep exactness), med3
// clamps, trunc-as-floor. Exec-masked global fallback for |off| >= 1.
// ---------------------------------------------------------------------------
template <int C_IN, int C_OUT, int NW, int DEFORM>
__global__ __launch_bounds__(NW * 64) void conv_s1_mfma(
    const unsigned short* __restrict__ in, const unsigned short* __restrict__ wT,
    const float* __restrict__ bias, unsigned short* __restrict__ out,
    int H, int W, int relu)
{
    constexpr int LDSTR  = C_IN + 8;
    constexpr int KSTEPS = C_IN / 32;
    constexpr int CH8    = C_IN / 8;
    constexpr int COPB   = 32 * (NW / 4);
    static_assert(!DEFORM || COPB == 64, "deform fusion expects 64 conv ch/block");
    constexpr int SSTR   = 40;                          // sample-buffer pixel stride
    constexpr int S_CONV = 18 * 18 * LDSTR;
    constexpr int S_SMP  = DEFORM ? 4 * 100 * SSTR : 0; // 16000 ush = 32 KB
    constexpr int S_A    = (S_CONV > S_SMP) ? S_CONV : S_SMP;
    __shared__ __align__(16) unsigned short s_in[S_A];
    __shared__ __align__(16) unsigned short s_off[DEFORM ? 16 * 16 * 64 : 8];

    const int tid   = threadIdx.x;
    const int wave  = tid >> 6;
    const int wv    = wave & 3;
    const int csub  = wave >> 2;
    const int lane  = tid & 63;
    const int mlane = lane & 15;
    const int quad  = lane >> 4;

    const int nCo  = C_OUT / COPB;
    const int b    = blockIdx.z / nCo;
    const int coB  = (blockIdx.z - b * nCo) * COPB + csub * 32;
    const int row0 = blockIdx.y * 16;
    const int col0 = blockIdx.x * 16;

    for (int idx = tid; idx < 18 * 18 * CH8; idx += NW * 64) {
        int pixel = idx / CH8;
        int ch    = (idx - pixel * CH8) * 8;
        int pr    = pixel / 18;
        int pc    = pixel - pr * 18;
        int gr = row0 - 1 + pr, gc = col0 - 1 + pc;
        ulonglong2 v; v.x = 0; v.y = 0;
        if ((unsigned)gr < (unsigned)H && (unsigned)gc < (unsigned)W)
            v = *(const ulonglong2*)&in[((b * H + gr) * W + gc) * C_IN + ch];
        *(ulonglong2*)&s_in[pixel * LDSTR + ch] = v;
    }

    // T14: issue sample-neighborhood loads now; the staging barrier's
    // vmcnt(0) drain hides their latency for free.
    ulonglong2 sv[4];
    if (DEFORM) {
        const int zbase = (blockIdx.z - b * nCo) * 32;
        const int Hh = H >> 1, Wh = W >> 1;
        const int r8 = blockIdx.y * 8, c8 = blockIdx.x * 8;
        #pragma unroll
        for (int j = 0; j < 4; ++j) {
            const int idx = tid + j * (NW * 64);
            if (idx < 1600) {
                const int pixel = idx >> 2;
                const int chq   = (idx & 3) * 8;
                const int reg   = pixel / 100;
                const int rem   = pixel - reg * 100;
                const int rr_   = rem / 10;
                const int cc_   = rem - rr_ * 10;
                int gr = r8 + (reg >> 1) * Hh - 1 + rr_;
                int gc = c8 + (reg & 1)  * Wh - 1 + cc_;
                gr = gr < 0 ? 0 : (gr > H - 1 ? H - 1 : gr);
                gc = gc < 0 ? 0 : (gc > W - 1 ? W - 1 : gc);
                sv[j] = *(const ulonglong2*)&in[((b * H + gr) * W + gc) * C_IN + zbase + chq];
            }
        }
    }
    __syncthreads();

    f32x4 acc[2][4];
    #pragma unroll
    for (int mt = 0; mt < 2; ++mt)
        #pragma unroll
        for (int t = 0; t < 4; ++t) acc[mt][t] = (f32x4)(0.f);

    #pragma unroll 1
    for (int kk = 0; kk < KSTEPS; ++kk) {
        short8 A[2][9];
        #pragma unroll
        for (int mt = 0; mt < 2; ++mt)
            #pragma unroll
            for (int tap = 0; tap < 9; ++tap)
                A[mt][tap] = *(const short8*)&wT[
                    ((((tap * (C_OUT / 16) + (coB >> 4) + mt) * (C_IN / 8))
                      + kk * 4 + quad) * 16 + mlane) * 8];

        const unsigned short* sb =
            &s_in[(wv * 4 * 18 + mlane) * LDSTR + kk * 32 + quad * 8];
        #pragma unroll
        for (int t = 0; t < 4; ++t) {
            #pragma unroll
            for (int tap = 0; tap < 9; ++tap) {
                const int dy = tap / 3, dx = tap % 3;
                short8 Bf = *(const short8*)&sb[((t + dy) * 18 + dx) * LDSTR];
                acc[0][t] = __builtin_amdgcn_mfma_f32_16x16x32_bf16(A[0][tap], Bf, acc[0][t], 0, 0, 0);
                acc[1][t] = __builtin_amdgcn_mfma_f32_16x16x32_bf16(A[1][tap], Bf, acc[1][t], 0, 0, 0);
            }
        }
    }

    if (!DEFORM) {
        #pragma unroll
        for (int mt = 0; mt < 2; ++mt) {
            const int cb = coB + mt * 16 + quad * 4;
            float4 bv;
            if (bias) bv = *(const float4*)&bias[cb]; else { bv.x = bv.y = bv.z = bv.w = 0.f; }
            #pragma unroll
            for (int t = 0; t < 4; ++t) {
                const int row = row0 + wv * 4 + t, col = col0 + mlane;
                float o0 = acc[mt][t][0] + bv.x, o1 = acc[mt][t][1] + bv.y;
                float o2 = acc[mt][t][2] + bv.z, o3 = acc[mt][t][3] + bv.w;
                if (relu) {
                    o0 = fmaxf(o0, 0.f); o1 = fmaxf(o1, 0.f);
                    o2 = fmaxf(o2, 0.f); o3 = fmaxf(o3, 0.f);
                }
                ushort4 pk; pk.x = f2b(o0); pk.y = f2b(o1); pk.z = f2b(o2); pk.w = f2b(o3);
                *(ushort4*)&out[((b * H + row) * W + col) * C_OUT + cb] = pk;
            }
        }
    } else {
        const int zb    = blockIdx.z - b * nCo;
        const int zbase = zb * 32;
        const int Hh = H >> 1, Wh = W >> 1;
        const int r8 = blockIdx.y * 8, c8 = blockIdx.x * 8;

        __syncthreads();   // conv reads of s_in complete; s_in is reused below

        // ---- phase A: offsets -> s_off (ch-XOR swizzled); staged regs -> s_in
        #pragma unroll
        for (int mt = 0; mt < 2; ++mt) {
            const int cb  = csub * 32 + mt * 16 + quad * 4;          // block-local ch
            const int swc = cb ^ ((mlane & 7) << 3);
            #pragma unroll
            for (int t = 0; t < 4; ++t) {
                ushort4 pk;
                pk.x = f2b(acc[mt][t][0]); pk.y = f2b(acc[mt][t][1]);
                pk.z = f2b(acc[mt][t][2]); pk.w = f2b(acc[mt][t][3]);
                *(ushort4*)&s_off[((wv * 4 + t) * 16 + mlane) * 64 + swc] = pk;
            }
        }
        #pragma unroll
        for (int j = 0; j < 4; ++j) {
            const int idx = tid + j * (NW * 64);
            if (idx < 1600) {
                const int pixel = idx >> 2;
                const int chq   = (idx & 3) * 8;
                *(ulonglong2*)&s_in[pixel * SSTR + chq] = sv[j];
            }
        }
        __syncthreads();

        // ---- phase B: bilinear sampling from LDS neighborhoods
        const int ci   = tid & 31;          // sample channel (within this co-block)
        const int slot = tid >> 5;          // 0..15 position slot
        const unsigned short* xb = in  + (long)b * H * W * C_IN + zbase + ci;
        unsigned short*       ob = out + (long)b * H * W * C_IN + zbase + ci;
        const float Hm1 = (float)(H - 1), Wm1 = (float)(W - 1);

        #pragma unroll 4
        for (int s = 0; s < 8; ++s) {
            const int pos = slot + s * 16;          // 0..127
            const int rl  = pos >> 4;               // 0..7 sample row in tile
            const int cl  = (pos >> 1) & 7;         // 0..7 sample col in tile
            const int chf = pos & 1;                // col-half select
            const int lr  = rl * 2 + chf;           // conv-local row
            const int lc  = cl * 2;                 // conv-local col (even)
            const int bix = (lr * 16 + lc) * 64;
            const ushort2 roP = *(const ushort2*)&s_off[bix +      ((2 * ci) ^ ((lc & 7) << 3))];
            const ushort2 coP = *(const ushort2*)&s_off[bix + 64 + ((2 * ci) ^ (((lc + 1) & 7) << 3))];
            #pragma unroll
            for (int ih = 0; ih < 2; ++ih) {
                const int R0 = r8 + ih * Hh, C0 = c8 + chf * Wh;
                const int rowg = R0 + rl, cg = C0 + cl;
                const float rr = __builtin_amdgcn_fmed3f(
                    b2f(ih ? roP.y : roP.x) + (float)rowg, 0.f, Hm1);
                const float cc = __builtin_amdgcn_fmed3f(
                    b2f(ih ? coP.y : coP.x) + (float)cg, 0.f, Wm1);
                const int irf = (int)rr, icf = (int)cc;   // rr,cc >= 0: trunc == floor
                const float fr = rr - (float)irf;
                const float fc = cc - (float)icf;
                const int lr0 = irf - R0 + 1;       // LDS row 0..9 when in-box
                const int lc0 = icf - C0 + 1;
                float v00, v01, v10, v11;
                if ((unsigned)lr0 <= 8u && (unsigned)lc0 <= 8u) {
                    const unsigned short* sp =
                        &s_in[((ih * 2 + chf) * 100 + lr0 * 10 + lc0) * SSTR + ci];
                    v00 = b2f(sp[0]);
                    v01 = b2f(sp[SSTR]);
                    v10 = b2f(sp[10 * SSTR]);
                    v11 = b2f(sp[11 * SSTR]);
                } else {                             // rare: |off| >= 1
                    const int dr1 = (fr > 0.f) ? 1 : 0;
                    const int dc1 = (fc > 0.f) ? 1 : 0;
                    const int idx00 = (irf * W + icf) * C_IN;
                    const int dr = dr1 * W * C_IN, dc = dc1 * C_IN;
                    v00 = b2f(xb[idx00]);
                    v01 = b2f(xb[idx00 + dc]);
                    v10 = b2f(xb[idx00 + dr]);
                    v11 = b2f(xb[idx00 + dr + dc]);
                }
                const float vt = v00 + (v10 - v00) * fr;
                const float vb = v01 + (v11 - v01) * fr;
                const float rs = vt + (vb - vt) * fc;
                ob[(rowg * W + cg) * C_IN] = f2b(rs);
            }
        }
    }
}

// ---------------------------------------------------------------------------
// 3x3 conv, pad 1, stride 2, NHWC bf16. Block: 8x8 out px x (NW/4) co-blocks.
// ---------------------------------------------------------------------------
template <int C_IN, int C_OUT, int NW>
__global__ __launch_bounds__(NW * 64) void conv_s2_mfma(
    const unsigned short* __restrict__ in, const unsigned short* __restrict__ wT,
    const float* __restrict__ bias, unsigned short* __restrict__ out,
    int H_in, int W_in, int relu)
{
    constexpr int LDSTR  = C_IN + 8;
    constexpr int KSTEPS = C_IN / 32;
    constexpr int CH8    = C_IN / 8;
    constexpr int COPB   = 32 * (NW / 4);
    __shared__ unsigned short s_in[17 * 17 * LDSTR];

    const int tid   = threadIdx.x;
    const int wave  = tid >> 6;
    const int wv    = wave & 3;
    const int csub  = wave >> 2;
    const int lane  = tid & 63;
    const int mlane = lane & 15;
    const int quad  = lane >> 4;

    const int H_out = H_in >> 1, W_out = W_in >> 1;
    const int nCo   = C_OUT / COPB;
    const int b     = blockIdx.z / nCo;
    const int coB   = (blockIdx.z - b * nCo) * COPB + csub * 32;
    const int orow0 = blockIdx.y * 8, ocol0 = blockIdx.x * 8;
    const int irow0 = orow0 * 2 - 1,  icol0 = ocol0 * 2 - 1;

    for (int idx = tid; idx < 17 * 17 * CH8; idx += NW * 64) {
        int pixel = idx / CH8;
        int ch    = (idx - pixel * CH8) * 8;
        int pr    = pixel / 17;
        int pc    = pixel - pr * 17;
        int gr = irow0 + pr, gc = icol0 + pc;
        ulonglong2 v; v.x = 0; v.y = 0;
        if ((unsigned)gr < (unsigned)H_in && (unsigned)gc < (unsigned)W_in)
            v = *(const ulonglong2*)&in[((b * H_in + gr) * W_in + gc) * C_IN + ch];
        *(ulonglong2*)&s_in[pixel * LDSTR + ch] = v;
    }
    __syncthreads();

    f32x4 acc[2];
    acc[0] = (f32x4)(0.f); acc[1] = (f32x4)(0.f);

    const int plr = wv * 2 + (mlane >> 3);
    const int plc = mlane & 7;

    #pragma unroll 1
    for (int kk = 0; kk < KSTEPS; ++kk) {
        short8 A[2][9];
        #pragma unroll
        for (int mt = 0; mt < 2; ++mt)
            #pragma unroll
            for (int tap = 0; tap < 9; ++tap)
                A[mt][tap] = *(const short8*)&wT[
                    ((((tap * (C_OUT / 16) + (coB >> 4) + mt) * (C_IN / 8))
                      + kk * 4 + quad) * 16 + mlane) * 8];

        const unsigned short* sb0 =
            &s_in[(plr * 2 * 17 + plc * 2) * LDSTR + kk * 32 + quad * 8];
        #pragma unroll
        for (int tap = 0; tap < 9; ++tap) {
            const int dy = tap / 3, dx = tap % 3;
            short8 Bf = *(const short8*)&sb0[(dy * 17 + dx) * LDSTR];
            acc[0] = __builtin_amdgcn_mfma_f32_16x16x32_bf16(A[0][tap], Bf, acc[0], 0, 0, 0);
            acc[1] = __builtin_amdgcn_mfma_f32_16x16x32_bf16(A[1][tap], Bf, acc[1], 0, 0, 0);
        }
    }

    const int row = orow0 + plr, col = ocol0 + plc;
    #pragma unroll
    for (int mt = 0; mt < 2; ++mt) {
        const int cb = coB + mt * 16 + quad * 4;
        float4 bv;
        if (bias) bv = *(const float4*)&bias[cb]; else { bv.x = bv.y = bv.z = bv.w = 0.f; }
        float o0 = acc[mt][0] + bv.x, o1 = acc[mt][1] + bv.y;
        float o2 = acc[mt][2] + bv.z, o3 = acc[mt][3] + bv.w;
        if (relu) {
            o0 = fmaxf(o0, 0.f); o1 = fmaxf(o1, 0.f);
            o2 = fmaxf(o2, 0.f); o3 = fmaxf(o3, 0.f);
        }
        ushort4 pk; pk.x = f2b(o0); pk.y = f2b(o1); pk.z = f2b(o2); pk.w = f2b(o3);
        *(ushort4*)&out[((b * H_out + row) * W_out + col) * C_OUT + cb] = pk;
    }
}

// ---------------------------------------------------------------------------
// x: fp32 NCHW (C=32) -> bf16 NHWC via LDS transpose. Block: 32ch x 64 px.
// ---------------------------------------------------------------------------
__global__ __launch_bounds__(256) void nchw2nhwc(
    const float* __restrict__ x, unsigned short* __restrict__ out, int HW)
{
    __shared__ float s[32][65];
    const int b = blockIdx.y, p0 = blockIdx.x * 64;
    const int tid = threadIdx.x;
    #pragma unroll
    for (int k = 0; k < 8; ++k) {
        int e = tid + k * 256, ci = e >> 6, p = e & 63;
        s[ci][p] = x[(b * 32 + ci) * HW + p0 + p];
    }
    __syncthreads();
    #pragma unroll
    for (int k = 0; k < 8; ++k) {
        int e = tid + k * 256, p = e >> 5, ci = e & 31;
        out[(b * HW + p0 + p) * 32 + ci] = f2b(s[ci][p]);
    }
}

// all 7 weight transforms: fp32 OIHW -> bf16 [tap][co/16][ci/8][co%16][8ci]
struct WTArgs {
    const float* src[7];
    unsigned short* dst[7];
    int co[7], ci[7], n[7];
};
__global__ __launch_bounds__(256) void wtrans_all(WTArgs a)
{
    const int i = blockIdx.x * 256 + threadIdx.x;
    #pragma unroll
    for (int s = 0; s < 7; ++s) {
        if (i < a.n[s]) {
            const int nci8  = a.ci[s] >> 3;
            const int nco16 = a.co[s] >> 4;
            const int ci_in  = i & 7;
            const int t1     = i >> 3;
            const int co_in  = t1 & 15;
            const int t2     = t1 >> 4;
            const int ci_grp = t2 % nci8;
            const int t3     = t2 / nci8;
            const int co_blk = t3 % nco16;
            const int tap    = t3 / nco16;
            const int co = co_blk * 16 + co_in;
            const int ci = ci_grp * 8 + ci_in;
            a.dst[s][i] = f2b(a.src[s][(co * a.ci[s] + ci) * 9 + tap]);
        }
    }
}

// global avg pool over 32x32, NHWC bf16 (C=32) -> fp32 (B,C)
__global__ __launch_bounds__(256) void avgpool_nhwc(
    const unsigned short* __restrict__ in, float* __restrict__ out)
{
    const int b = blockIdx.x, tid = threadIdx.x;
    const int ci = tid & 31, pg = tid >> 5;
    float s = 0.f;
    for (int k = 0; k < 128; ++k) {
        int p = pg * 128 + k;
        s += b2f(in[(b * 1024 + p) * 32 + ci]);
    }
    __shared__ float red[8][32];
    red[pg][ci] = s;
    __syncthreads();
    if (tid < 32) {
        float t = 0.f;
        #pragma unroll
        for (int j = 0; j < 8; ++j) t += red[j][tid];
        out[b * 32 + tid] = t * (1.f / 1024.f);
    }
}

__global__ __launch_bounds__(256) void sentinel(float* out, int n, float v)
{
    int i = blockIdx.x * 256 + threadIdx.x;
    if (i < n) out[i] = v;
}

extern "C" void kernel_launch(void* const* d_in, const int* in_sizes, int n_in,
                              void* d_out, int out_size, void* d_ws, size_t ws_size,
                              hipStream_t stream) {
    (void)in_sizes; (void)n_in; (void)out_size;
    const float* x   = (const float*)d_in[0];
    const float* w1  = (const float*)d_in[1];
    const float* b1  = (const float*)d_in[2];
    const float* ow1 = (const float*)d_in[3];
    const float* w2  = (const float*)d_in[4];
    const float* b2  = (const float*)d_in[5];
    const float* ow2 = (const float*)d_in[6];
    const float* w3  = (const float*)d_in[7];
    const float* b3  = (const float*)d_in[8];
    const float* ow3 = (const float*)d_in[9];
    const float* w4  = (const float*)d_in[10];
    const float* b4  = (const float*)d_in[11];
    float* out = (float*)d_out;
    unsigned short* wsu = (unsigned short*)d_ws;

    const size_t XB = 0;
    const size_t HA = 33554432;
    const size_t DC = 134217728;
    const size_t WB = 167772160;
    const size_t total_us = WB + 165888;
    if (ws_size < total_us * 2) {
        sentinel<<<2, 256, 0, stream>>>(out, 512, 12345.0f);
        return;
    }
    unsigned short* xb = wsu + XB;
    unsigned short* hA = wsu + HA;
    unsigned short* dC = wsu + DC;
    unsigned short* wt1  = wsu + WB;
    unsigned short* owt1 = wt1 + 9216;
    unsigned short* wt2  = owt1 + 18432;
    unsigned short* owt2 = wt2 + 18432;
    unsigned short* wt3  = owt2 + 73728;
    unsigned short* owt3 = wt3 + 18432;
    unsigned short* wt4  = owt3 + 18432;

    WTArgs wa;
    wa.src[0] = w1;  wa.dst[0] = wt1;  wa.co[0] = 32;  wa.ci[0] = 32; wa.n[0] = 9216;
    wa.src[1] = ow1; wa.dst[1] = owt1; wa.co[1] = 64;  wa.ci[1] = 32; wa.n[1] = 18432;
    wa.src[2] = w2;  wa.dst[2] = wt2;  wa.co[2] = 64;  wa.ci[2] = 32; wa.n[2] = 18432;
    wa.src[3] = ow2; wa.dst[3] = owt2; wa.co[3] = 128; wa.ci[3] = 64; wa.n[3] = 73728;
    wa.src[4] = w3;  wa.dst[4] = wt3;  wa.co[4] = 32;  wa.ci[4] = 64; wa.n[4] = 18432;
    wa.src[5] = ow3; wa.dst[5] = owt3; wa.co[5] = 64;  wa.ci[5] = 32; wa.n[5] = 18432;
    wa.src[6] = w4;  wa.dst[6] = wt4;  wa.co[6] = 32;  wa.ci[6] = 32; wa.n[6] = 9216;
    wtrans_all<<<288, 256, 0, stream>>>(wa);

    nchw2nhwc<<<dim3(1024, 16), 256, 0, stream>>>(x, xb, 65536);

    // L1: conv1 (32->32, 256x256, s1, relu)
    conv_s1_mfma<32, 32, 4, 0><<<dim3(16, 16, 16), 256, 0, stream>>>(xb, wt1, b1, hA, 256, 256, 1);
    // offconv1 (32->64) fused with deformable sampling: hA -> dC
    conv_s1_mfma<32, 64, 8, 1><<<dim3(16, 16, 16), 512, 0, stream>>>(hA, owt1, nullptr, dC, 256, 256, 0);

    // L2: conv2 (32->64, s2) 256->128
    conv_s2_mfma<32, 64, 8><<<dim3(16, 16, 16), 512, 0, stream>>>(dC, wt2, b2, hA, 256, 256, 1);
    // offconv2 (64->128) fused with deform: hA -> dC
    conv_s1_mfma<64, 128, 8, 1><<<dim3(8, 8, 32), 512, 0, stream>>>(hA, owt2, nullptr, dC, 128, 128, 0);

    // L3: conv3 (64->32, s2) 128->64
    conv_s2_mfma<64, 32, 4><<<dim3(8, 8, 16), 256, 0, stream>>>(dC, wt3, b3, hA, 128, 128, 1);
    // offconv3 (32->64) fused with deform: hA -> dC
    conv_s1_mfma<32, 64, 8, 1><<<dim3(4, 4, 16), 512, 0, stream>>>(hA, owt3, nullptr, dC, 64, 64, 0);

    // L4: conv4 (32->32, s2) 64->32
    conv_s2_mfma<32, 32, 4><<<dim3(4, 4, 16), 256, 0, stream>>>(dC, wt4, b4, hA, 64, 64, 1);
    avgpool_nhwc<<<16, 256, 0, stream>>>(hA, out);
}